// Round 1
// baseline (133.711 us; speedup 1.0000x reference)
//
#include <hip/hip_runtime.h>

// PCEN: x (B=32, T=4000, C=128) fp32.
//   ema[t] = w*x[t] + (1-w)*ema[t-1],  ema[0] = x[0]
//   out = (x / (FLOOR + ema)^alpha + delta)^(1/root) - delta^(1/root)
//
// R6 design (exact two-pass chunked linear-recurrence scan, LDS-vectorized):
//   K1: per chunk j, S_j = sum_i w(1-w)^{L-1-i} x[i]   (local sum, init 0)
//   K2: per (b,c), scan e_{j+1} = A e_j + S_j, A=(1-w)^L (Kogge-Stone, 1 wave)
//   K3: per chunk j, run recurrence from exact e_j + transcendental epilogue
// S_j / E_j are staged INSIDE d_out (rows j*CHUNK+1 / j*CHUNK of chunk j's own
// output region, overwritten by K3 after it reads them) -> no workspace.
//
// R6 change vs R5: K1/K3 previously did 4B/lane strided column loads/stores
// (thread c touching x[t,c] at 512B stride) — never vectorized by hipcc (G13).
// Now each block stages its contiguous 16KB chunk through LDS with float4
// (16B/lane) global accesses in BOTH directions; per-channel column access
// happens in LDS (lanes read consecutive floats -> conflict-free).
// Arithmetic is bit-identical to the harness-verified R5 math.

#define FLOOR_EPS 1e-12f

constexpr int Bn = 32;
constexpr int Tn = 4000;
constexpr int Cn = 128;
constexpr int NCHUNK = 125;          // 125 * 32 = 4000
constexpr int CHUNK  = 32;

// ---------------- K1: local weighted sums ----------------
__global__ __launch_bounds__(Cn) void k1_localsum(
    const float* __restrict__ x,
    const float* __restrict__ w_p,
    float* __restrict__ out)
{
    __shared__ float tile[CHUNK * Cn];           // 16 KB: this block's chunk
    const int tid = threadIdx.x;
    const int j = blockIdx.x;
    const int b = blockIdx.y;
    const size_t base = ((size_t)b * Tn + (size_t)j * CHUNK) * (size_t)Cn;

    // vectorized stage: 16KB = 1024 float4, 128 threads x 8 each (coalesced 16B/lane)
    const float4* __restrict__ g4 = (const float4*)(x + base);
    float4* t4 = (float4*)tile;
    #pragma unroll
    for (int k = 0; k < 8; ++k)
        t4[k * Cn + tid] = g4[k * Cn + tid];
    __syncthreads();

    const int c = tid;
    const float w   = fminf(fmaxf(w_p[c], 0.0f), 1.0f);
    const float omw = 1.0f - w;
    float s = 0.0f;
    #pragma unroll
    for (int k = 0; k < CHUNK; ++k)              // LDS column read: lanes
        s = fmaf(omw, s, w * tile[k * Cn + c]);  // consecutive -> conflict-free
    out[base + Cn + c] = s;                      // S_j row (row j*CHUNK+1)
}

// ---------------- K2: chunk-state scan (one wave per (b,c)) ----------------
__global__ __launch_bounds__(256) void k2_scan(
    const float* __restrict__ x,
    const float* __restrict__ w_p,
    float* __restrict__ out)
{
    const int wid  = (blockIdx.x * 256 + threadIdx.x) >> 6;  // 0..4095
    const int lane = threadIdx.x & 63;
    const int b = wid >> 7;        // 0..31
    const int c = wid & 127;       // 0..127

    const float w   = fminf(fmaxf(w_p[c], 0.0f), 1.0f);
    const float omw = 1.0f - w;
    // A = omw^CHUNK  (omw=0 -> log2=-inf -> A=0, correct; omw=1 -> A=1)
    const float A = __builtin_exp2f((float)CHUNK * __builtin_log2f(omw));

    const float* __restrict__ sb = out + (size_t)b * Tn * Cn + c;
    float* __restrict__ eb       = out + (size_t)b * Tn * Cn + c;

    // segment 1: chunks j = lane (0..63); segment 2: j = 64+lane (<125)
    float s1 = sb[((size_t)lane * CHUNK + 1) * Cn];
    float a1 = A;
    const int j2 = 64 + lane;
    float s2 = (j2 < NCHUNK) ? sb[((size_t)j2 * CHUNK + 1) * Cn] : 0.0f;
    float a2 = (j2 < NCHUNK) ? A : 1.0f;

    // inclusive Kogge-Stone scan of affine transforms (a,s): e -> a*e + s
    // compose(prev p, cur q) = (q.a*p.a, q.a*p.s + q.s)
    #pragma unroll
    for (int r = 1; r < 64; r <<= 1) {
        float ts = __shfl_up(s1, r, 64);
        float ta = __shfl_up(a1, r, 64);
        if (lane >= r) { s1 = fmaf(a1, ts, s1); a1 *= ta; }
        ts = __shfl_up(s2, r, 64);
        ta = __shfl_up(a2, r, 64);
        if (lane >= r) { s2 = fmaf(a2, ts, s2); a2 *= ta; }
    }

    const float e0 = x[(size_t)b * Tn * Cn + c];          // ema init = x[b,0,c]
    const float E1 = fmaf(a1, e0, s1);                    // E_{lane+1}
    const float E64 = __shfl(E1, 63, 64);                 // carry into segment 2
    const float E2 = fmaf(a2, E64, s2);                   // E_{65+lane}

    if (lane == 0) eb[0] = e0;                            // E_0 (row 0)
    eb[(size_t)(lane + 1) * CHUNK * Cn] = E1;             // E_1..E_64
    if (lane + 65 < NCHUNK)
        eb[(size_t)(lane + 65) * CHUNK * Cn] = E2;        // E_65..E_124
}

// ---------------- K3: apply recurrence + epilogue ----------------
__global__ __launch_bounds__(Cn) void k3_apply(
    const float* __restrict__ x,
    const float* __restrict__ alpha_p,
    const float* __restrict__ delta_p,
    const float* __restrict__ root_p,
    const float* __restrict__ w_p,
    float* __restrict__ out)
{
    __shared__ float tile[CHUNK * Cn];           // 16 KB: x chunk, then results
    const int tid = threadIdx.x;
    const int j = blockIdx.x;
    const int b = blockIdx.y;
    const size_t base = ((size_t)b * Tn + (size_t)j * CHUNK) * (size_t)Cn;

    // vectorized stage of the x chunk (16B/lane)
    const float4* __restrict__ g4 = (const float4*)(x + base);
    float4* t4 = (float4*)tile;
    #pragma unroll
    for (int k = 0; k < 8; ++k)
        t4[k * Cn + tid] = g4[k * Cn + tid];

    const int c = tid;
    const float alpha  = fminf(alpha_p[c], 1.0f);
    const float root   = fmaxf(root_p[c], 1.0f);
    const float delta  = delta_p[c];
    const float oor    = 1.0f / root;
    const float droot  = __builtin_exp2f(oor * __builtin_log2f(delta));
    const float nalpha = -alpha;
    const float w      = fminf(fmaxf(w_p[c], 0.0f), 1.0f);
    const float omw    = 1.0f - w;

    const float E = out[base + c];   // exact E_j written by K2 (own region,
                                     // read before this block's final store)
    __syncthreads();

    float acc = E;
    #pragma unroll
    for (int k = 0; k < CHUNK; ++k) {
        const float xv = tile[k * Cn + c];       // conflict-free column read
        acc = fmaf(omw, acc, w * xv);
        const float l  = __builtin_log2f(FLOOR_EPS + acc);
        const float t1 = xv * __builtin_exp2f(nalpha * l);
        tile[k * Cn + c] =                       // result back in place
            __builtin_exp2f(oor * __builtin_log2f(t1 + delta)) - droot;
    }
    __syncthreads();

    // vectorized store (16B/lane), overwrites the staged S/E rows last
    float4* o4 = (float4*)(out + base);
    #pragma unroll
    for (int k = 0; k < 8; ++k)
        o4[k * Cn + tid] = t4[k * Cn + tid];
}

extern "C" void kernel_launch(void* const* d_in, const int* in_sizes, int n_in,
                              void* d_out, int out_size, void* d_ws, size_t ws_size,
                              hipStream_t stream) {
    const float* x     = (const float*)d_in[0];
    const float* alpha = (const float*)d_in[1];
    const float* delta = (const float*)d_in[2];
    const float* root  = (const float*)d_in[3];
    const float* ew    = (const float*)d_in[4];
    float* out = (float*)d_out;

    dim3 grid(NCHUNK, Bn, 1);                     // 4000 blocks, 8000 waves
    k1_localsum<<<grid, Cn, 0, stream>>>(x, ew, out);
    // one wave per (b,c): 32*128 = 4096 waves = 1024 blocks x 256 threads
    k2_scan<<<dim3((Bn * Cn * 64) / 256), 256, 0, stream>>>(x, ew, out);
    k3_apply<<<grid, Cn, 0, stream>>>(x, alpha, delta, root, ew, out);
}